// Round 1
// baseline (149.479 us; speedup 1.0000x reference)
//
#include <hip/hip_runtime.h>

// TT-linear: y = x[16384,784] @ W[784,512] + bias; out = softmax(relu(y), axis=1)
// W is materialized from the 4 TT cores (cheap), packed as bf16 MFMA B-fragments.
//
// ws layout (bytes):
//   [0,            1605632)  T123  : 401408 f32  [ijk(196)][pqe(128)][t(16)]
//   [1605632,      1641472)  T12   : 8960   f32  [ij(28)][pq(16)][s(20)]
//   [1641472,      2460672)  Wp    : 409600 bf16 [(tn*25+tk)*64+lane]*8+j
//                                    = W[k=tk*32+(lane>>4)*8+j][n=tn*16+(lane&15)]

typedef __attribute__((ext_vector_type(8))) short short8;
typedef __attribute__((ext_vector_type(4))) float floatx4;

#define T123_OFF 0
#define T12_OFF  1605632
#define WP_OFF   1641472

__device__ __forceinline__ unsigned int pack2_bf16(float a, float b) {
    // round-half-up to bf16 (tie behavior differs from RNE only on exact ties)
    unsigned int ua = __float_as_uint(a);
    unsigned int ub = __float_as_uint(b);
    return ((ub + 0x8000u) & 0xFFFF0000u) | ((ua + 0x8000u) >> 16);
}

// ---------- prep 1: T12[ij][pq][s] = sum_r core1[i,p,r]*core2[r,j,q,s] ----------
__global__ void prep_t12(const float* __restrict__ c1, const float* __restrict__ c2,
                         float* __restrict__ t12) {
    int idx = blockIdx.x * 256 + threadIdx.x;
    if (idx >= 8960) return;
    int s  = idx % 20;
    int pq = (idx / 20) & 15;
    int ij = idx / 320;
    int i = ij >> 2, j2 = ij & 3;
    int p = pq >> 2, q  = pq & 3;
    float acc = 0.f;
    #pragma unroll
    for (int r = 0; r < 20; ++r)
        acc += c1[i * 80 + p * 20 + r] * c2[r * 320 + j2 * 80 + q * 20 + s];
    t12[idx] = acc;
}

// ---------- prep 2: T123[ijk][pqe][t] = sum_s T12[ij][pq][s]*core3[s,k3,e,t] ----------
__global__ void prep_t123(const float* __restrict__ t12, const float* __restrict__ c3,
                          float* __restrict__ t123) {
    int idx = blockIdx.x * 256 + threadIdx.x;
    if (idx >= 401408) return;
    int t   = idx & 15;
    int pqe = (idx >> 4) & 127;
    int ijk = idx >> 11;
    int k3 = ijk % 7;
    int ij = ijk / 7;
    int e  = pqe & 7;
    int pq = pqe >> 3;
    float acc = 0.f;
    const float* tp = t12 + (ij * 16 + pq) * 20;
    const float* cp = c3 + k3 * 128 + e * 16 + t;
    #pragma unroll
    for (int s = 0; s < 20; ++s)
        acc += tp[s] * cp[s * 896];
    t123[idx] = acc;
}

// ---------- prep 3: W bf16, packed in B-fragment layout, K padded to 800 ----------
__global__ void prep_wp(const float* __restrict__ t123, const float* __restrict__ c4,
                        short* __restrict__ wp) {
    int idx = blockIdx.x * 256 + threadIdx.x;
    if (idx >= 409600) return;
    int j    = idx & 7;
    int lane = (idx >> 3) & 63;
    int tkt  = idx >> 9;
    int tk = tkt % 25;
    int tn = tkt / 25;
    int k = tk * 32 + (lane >> 4) * 8 + j;
    int n = tn * 16 + (lane & 15);
    float v = 0.f;
    if (k < 784) {
        int l  = k & 3;
        int k3 = (k >> 2) % 7;
        int ij = k / 28;
        int f4 = n & 3;
        int e  = (n >> 2) & 7;
        int q  = (n >> 5) & 3;
        int p  = n >> 7;
        int ijk = ij * 7 + k3;
        int pqe = p * 32 + q * 8 + e;
        const float* tp = t123 + (size_t)(ijk * 128 + pqe) * 16;
        const float* cp = c4 + l * 4 + f4;
        float a = 0.f;
        #pragma unroll
        for (int t = 0; t < 16; ++t)
            a += tp[t] * cp[t * 16];
        v = a;
    }
    unsigned int u = __float_as_uint(v);
    wp[idx] = (short)(((u + 0x7FFFu + ((u >> 16) & 1)) >> 16) & 0xFFFF);
}

// ---------- main: GEMM + bias + relu + softmax, barrier-free K-loop ----------
// grid 512 (32 rows each), block 256 = 4 waves; wave w owns rows[0..31], cols[w*128..+128)
__global__ __launch_bounds__(256, 2) void tt_gemm(const float* __restrict__ x,
                                                  const short* __restrict__ wp,
                                                  const float* __restrict__ bias,
                                                  float* __restrict__ out) {
    const int tid  = threadIdx.x;
    const int w    = tid >> 6;        // wave index = N-strip
    const int lane = tid & 63;
    const int quad = lane >> 4;
    const int lid  = lane & 15;
    const int m_base = blockIdx.x * 32;
    const int tn_base = w * 8;        // global n-tile base for this wave

    floatx4 acc[2][8];
    #pragma unroll
    for (int a = 0; a < 2; ++a)
        #pragma unroll
        for (int b = 0; b < 8; ++b)
            acc[a][b] = floatx4{0.f, 0.f, 0.f, 0.f};

    for (int tk = 0; tk < 25; ++tk) {
        const int k0 = tk * 32;
        const int kk = k0 + quad * 8;   // this lane's 8-element k-base

        // A fragments: 2 m-tiles, 8 consecutive fp32 each, packed to bf16
        short8 afrag[2];
        #pragma unroll
        for (int mt = 0; mt < 2; ++mt) {
            const int row = m_base + mt * 16 + lid;
            floatx4 v0 = floatx4{0.f, 0.f, 0.f, 0.f};
            floatx4 v1 = floatx4{0.f, 0.f, 0.f, 0.f};
            if (kk < 784) {                      // predicate off the zero-padded tail
                const floatx4* p = (const floatx4*)(x + (size_t)row * 784 + kk);
                v0 = p[0];
                v1 = p[1];
            }
            union { short8 s; unsigned int u[4]; } af;
            af.u[0] = pack2_bf16(v0.x, v0.y);
            af.u[1] = pack2_bf16(v0.z, v0.w);
            af.u[2] = pack2_bf16(v1.x, v1.y);
            af.u[3] = pack2_bf16(v1.z, v1.w);
            afrag[mt] = af.s;
        }

        // B fragments: one coalesced 16B load per n-tile (L2-resident)
        short8 bfrag[8];
        #pragma unroll
        for (int nt = 0; nt < 8; ++nt)
            bfrag[nt] = *(const short8*)(wp + (((size_t)(tn_base + nt) * 25 + tk) * 64 + lane) * 8);

        #pragma unroll
        for (int nt = 0; nt < 8; ++nt) {
            acc[0][nt] = __builtin_amdgcn_mfma_f32_16x16x32_bf16(afrag[0], bfrag[nt], acc[0][nt], 0, 0, 0);
            acc[1][nt] = __builtin_amdgcn_mfma_f32_16x16x32_bf16(afrag[1], bfrag[nt], acc[1][nt], 0, 0, 0);
        }
    }

    // ---- epilogue: bias + relu + exp, row-sum, softmax scale, store ----
    __shared__ float part[4][32];

    float bias_v[8];
    #pragma unroll
    for (int nt = 0; nt < 8; ++nt)
        bias_v[nt] = bias[w * 128 + nt * 16 + lid];

    float rsum[2][4];
    #pragma unroll
    for (int mt = 0; mt < 2; ++mt) {
        #pragma unroll
        for (int reg = 0; reg < 4; ++reg) {
            float s = 0.f;
            #pragma unroll
            for (int nt = 0; nt < 8; ++nt) {
                float v = acc[mt][nt][reg] + bias_v[nt];
                v = fmaxf(v, 0.f);
                float e = __expf(v);
                acc[mt][nt][reg] = e;
                s += e;
            }
            // reduce across the 16 lanes of this quad (same output row)
            s += __shfl_xor(s, 1, 64);
            s += __shfl_xor(s, 2, 64);
            s += __shfl_xor(s, 4, 64);
            s += __shfl_xor(s, 8, 64);
            rsum[mt][reg] = s;
        }
    }

    if (lid == 0) {
        #pragma unroll
        for (int mt = 0; mt < 2; ++mt)
            #pragma unroll
            for (int reg = 0; reg < 4; ++reg)
                part[w][mt * 16 + quad * 4 + reg] = rsum[mt][reg];
    }
    __syncthreads();

    #pragma unroll
    for (int mt = 0; mt < 2; ++mt) {
        #pragma unroll
        for (int reg = 0; reg < 4; ++reg) {
            const int rl = mt * 16 + quad * 4 + reg;
            const float tot = part[0][rl] + part[1][rl] + part[2][rl] + part[3][rl];
            const float inv = 1.0f / tot;
            const int row_g = m_base + rl;
            #pragma unroll
            for (int nt = 0; nt < 8; ++nt)
                out[(size_t)row_g * 512 + w * 128 + nt * 16 + lid] = acc[mt][nt][reg] * inv;
        }
    }
}

extern "C" void kernel_launch(void* const* d_in, const int* in_sizes, int n_in,
                              void* d_out, int out_size, void* d_ws, size_t ws_size,
                              hipStream_t stream) {
    const float* x    = (const float*)d_in[0];
    const float* c1   = (const float*)d_in[1];
    const float* c2   = (const float*)d_in[2];
    const float* c3   = (const float*)d_in[3];
    const float* c4   = (const float*)d_in[4];
    const float* bias = (const float*)d_in[5];
    float* out = (float*)d_out;

    char* ws = (char*)d_ws;
    float* t123 = (float*)(ws + T123_OFF);
    float* t12  = (float*)(ws + T12_OFF);
    short* wp   = (short*)(ws + WP_OFF);

    prep_t12 <<<35,   256, 0, stream>>>(c1, c2, t12);
    prep_t123<<<1568, 256, 0, stream>>>(t12, c3, t123);
    prep_wp  <<<1600, 256, 0, stream>>>(t123, c4, wp);
    tt_gemm  <<<512,  256, 0, stream>>>(x, wp, bias, out);
}